// Round 4
// baseline (448.533 us; speedup 1.0000x reference)
//
#include <hip/hip_runtime.h>

// FinePreprocess: gather 5x5 windows (stride 4, pad 2) from two NCHW fp32
// feature maps at M random (batch, grid-idx) points.
// Output flat layout (per map): (M, C, 5, 5).
//
// R4 = R3 with compile fix: __builtin_nontemporal_store needs a plain
// vector type, not HIP's float4 struct -> use ext_vector_type(4).
//
// R3 rationale: R2 was random-access-bound (43% HBM peak, VALU 2%,
// requests well under issue ceiling). Counting-sort the 12000 jobs by
// (map, b, idx) so concurrent blocks sweep the feature planes in near
// row-major order: L2 captures duplicate windows (~14% exact dups;
// 6000 draws over 19200 bins) + neighbor-line overlap, and DRAM sees
// page-local traffic. Output uses nontemporal stores (write-once data
// must not evict gather lines from the 32 MB L2).

#define MPTS  6000
#define NCH   128
#define FH    240
#define FW    320
#define OUTW  80                  // (320 + 2*2 - 5)/4 + 1
#define LGRID 4800                // 60 * 80
#define NJOBS (2 * MPTS)          // 12000
#define NBINS (2 * 4 * LGRID)     // 38400 keys: (map, b, idx)
#define PTFLOATS (NCH * 25)       // 3200 floats = 12.8 KB per (map, point)

typedef float f2 __attribute__((ext_vector_type(2)));
typedef float f4 __attribute__((ext_vector_type(4)));

// ---- ws layout: [0, NBINS) int hist/offsets ; [NBINS, NBINS+NJOBS) sorted ids

__global__ __launch_bounds__(256) void zero_hist_k(int* __restrict__ h) {
    int i = blockIdx.x * 256 + threadIdx.x;
    if (i < NBINS) h[i] = 0;
}

__device__ __forceinline__ int job_key(int j, const int* b_ids,
                                       const int* i_ids, const int* j_ids) {
    int map = j >= MPTS;
    int m   = map ? j - MPTS : j;
    int idx = map ? j_ids[m] : i_ids[m];
    return map * (4 * LGRID) + b_ids[m] * LGRID + idx;
}

__global__ __launch_bounds__(256) void hist_k(
    const int* __restrict__ b_ids, const int* __restrict__ i_ids,
    const int* __restrict__ j_ids, int* __restrict__ h) {
    int j = blockIdx.x * 256 + threadIdx.x;
    if (j >= NJOBS) return;
    atomicAdd(&h[job_key(j, b_ids, i_ids, j_ids)], 1);
}

// Exclusive prefix sum over NBINS ints, single block of 1024 threads.
__global__ __launch_bounds__(1024) void scan_k(int* __restrict__ h) {
    __shared__ int sums[1024];
    const int t = threadIdx.x;
    const int per = (NBINS + 1023) / 1024;    // 38
    const int base = t * per;
    int vals[38];
    int local = 0;
#pragma unroll
    for (int k = 0; k < per; k++) {
        int i = base + k;
        int v = (i < NBINS) ? h[i] : 0;
        vals[k] = v; local += v;
    }
    sums[t] = local;
    __syncthreads();
    for (int off = 1; off < 1024; off <<= 1) {
        int v = (t >= off) ? sums[t - off] : 0;
        __syncthreads();
        sums[t] += v;
        __syncthreads();
    }
    int excl = (t == 0) ? 0 : sums[t - 1];
#pragma unroll
    for (int k = 0; k < per; k++) {
        int i = base + k;
        if (i < NBINS) { h[i] = excl; excl += vals[k]; }
    }
}

__global__ __launch_bounds__(256) void scatter_k(
    const int* __restrict__ b_ids, const int* __restrict__ i_ids,
    const int* __restrict__ j_ids, int* __restrict__ h, int* __restrict__ sorted) {
    int j = blockIdx.x * 256 + threadIdx.x;
    if (j >= NJOBS) return;
    int pos = atomicAdd(&h[job_key(j, b_ids, i_ids, j_ids)], 1);
    sorted[pos] = j;
}

__global__ __launch_bounds__(320) void fine_gather_kernel(
    const float* __restrict__ f0, const float* __restrict__ f1,
    const int* __restrict__ b_ids, const int* __restrict__ i_ids,
    const int* __restrict__ j_ids, const int* __restrict__ sorted,
    float* __restrict__ out)
{
    __shared__ __align__(16) float lds[PTFLOATS];

    const int job = sorted[blockIdx.x];
    const int map = job >= MPTS;
    const int m   = map ? job - MPTS : job;
    const float* __restrict__ feat = map ? f1 : f0;
    const int idx = map ? j_ids[m] : i_ids[m];
    const int b   = b_ids[m];

    const int gy = idx / OUTW;
    const int gx = idx - gy * OUTW;
    const int row0 = gy * 4 - 2;
    const int col0 = gx * 4 - 2;          // even; OOB left only when gx==0

    const int t = threadIdx.x;

    // Phase 1: 640 segments (c,r), 2 per thread; 5 contiguous floats each.
#pragma unroll
    for (int it = 0; it < 2; it++) {
        const int s = t + it * 320;
        const int c = s / 5;
        const int r = s - c * 5;
        const int row = row0 + r;
        const bool vrow = (row >= 0) & (row < FH);
        const float* src = feat + (((long)(b * NCH + c) * FH + row) * FW + col0);

        float v[5];
        if (vrow && (col0 >= 0)) {
            const f2* p = (const f2*)src;
            f2 a0 = p[0];
            f2 a1 = p[1];
            v[0] = a0.x; v[1] = a0.y; v[2] = a1.x; v[3] = a1.y;
            v[4] = src[4];
        } else {
#pragma unroll
            for (int k = 0; k < 5; k++) {
                const int cc = col0 + k;
                v[k] = (vrow && cc >= 0) ? src[k] : 0.0f;
            }
        }
        const int base = s * 5;
#pragma unroll
        for (int k = 0; k < 5; k++) lds[base + k] = v[k];
    }

    __syncthreads();

    // Phase 2: coalesced nontemporal f4 store of the 12.8 KB tile to the
    // job's ORIGINAL output slot.
    f4* __restrict__ dst = (f4*)(out + (long)job * PTFLOATS);
    const f4* sl = (const f4*)lds;
    for (int i = t; i < PTFLOATS / 4; i += 320)
        __builtin_nontemporal_store(sl[i], &dst[i]);
}

extern "C" void kernel_launch(void* const* d_in, const int* in_sizes, int n_in,
                              void* d_out, int out_size, void* d_ws, size_t ws_size,
                              hipStream_t stream) {
    const float* f0   = (const float*)d_in[0];
    const float* f1   = (const float*)d_in[1];
    const int* b_ids  = (const int*)d_in[4];
    const int* i_ids  = (const int*)d_in[5];
    const int* j_ids  = (const int*)d_in[6];
    float* out        = (float*)d_out;

    int* hist   = (int*)d_ws;             // NBINS ints
    int* sorted = hist + NBINS;           // NJOBS ints

    zero_hist_k<<<(NBINS + 255) / 256, 256, 0, stream>>>(hist);
    hist_k<<<(NJOBS + 255) / 256, 256, 0, stream>>>(b_ids, i_ids, j_ids, hist);
    scan_k<<<1, 1024, 0, stream>>>(hist);
    scatter_k<<<(NJOBS + 255) / 256, 256, 0, stream>>>(b_ids, i_ids, j_ids, hist, sorted);
    fine_gather_kernel<<<NJOBS, 320, 0, stream>>>(f0, f1, b_ids, i_ids, j_ids, sorted, out);
}